// Round 10
// baseline (345.562 us; speedup 1.0000x reference)
//
#include <hip/hip_runtime.h>
#include <stdint.h>

#define T_TOK 2048
#define H_DIM 1024
#define E_NUM 16
#define I_DIM 1024
#define TOTAL_ROWS (2 * T_TOK)   // exactly T*K assignment rows
#define CPAD 16                  // counts padded to one per 64B cacheline

typedef short bf16x8 __attribute__((ext_vector_type(8)));
typedef float f32x4 __attribute__((ext_vector_type(4)));

__device__ __forceinline__ void async_copy16(const void* g, void* l) {
  __builtin_amdgcn_global_load_lds(
      (const __attribute__((address_space(1))) void*)g,
      (__attribute__((address_space(3))) void*)l, 16, 0, 0);
}

// fp32 -> bf16 round-to-nearest-even (inputs finite)
__device__ __forceinline__ uint32_t f2bf(float f) {
  uint32_t u = __float_as_uint(f);
  return (u + 0x7FFFu + ((u >> 16) & 1u)) >> 16;
}
__device__ __forceinline__ uint32_t pk2bf(float lo, float hi) {
  return f2bf(lo) | (f2bf(hi) << 16);
}

// ---------------------------------------------------------------------------
// Workspace layout (bytes). Total ~28.5 MB.
// ---------------------------------------------------------------------------
#define WS_COUNTS 0
#define WS_OFFSETS 2048
#define WS_ROWS 4096                     // 2048*2 ints
#define WS_TOKENS 20480                  // 128 KiB
#define WS_WTS 151552                    // 128 KiB
#define WS_XBF 294912                    // 4 MiB bf16 x
#define WS_HBUF (WS_XBF + 4194304)       // 8 MiB bf16 h
#define WS_OBUF (WS_HBUF + 8388608)      // 16 MiB fp32 per-assignment out

// ---------------------------------------------------------------------------
// Kernel 1: router (fp32 exact) + x -> bf16. Wave-per-token.
// ---------------------------------------------------------------------------
__global__ __launch_bounds__(256) void router_kernel(
    const float* __restrict__ x, const float* __restrict__ rw,
    uint16_t* __restrict__ xbf, int* __restrict__ counts,
    int* __restrict__ tokens, float* __restrict__ wts,
    int* __restrict__ rows) {
  const int t = blockIdx.x * 4 + (threadIdx.x >> 6);
  const int lane = threadIdx.x & 63;

  float4 xv[4];
  float acc[E_NUM];
#pragma unroll
  for (int e = 0; e < E_NUM; ++e) acc[e] = 0.f;

#pragma unroll
  for (int rep = 0; rep < 4; ++rep) {
    const int h0 = rep * 256 + lane * 4;
    xv[rep] = *(const float4*)(x + (size_t)t * H_DIM + h0);
    uint2 p;
    p.x = pk2bf(xv[rep].x, xv[rep].y);
    p.y = pk2bf(xv[rep].z, xv[rep].w);
    *(uint2*)(xbf + (size_t)t * H_DIM + h0) = p;
  }

#pragma unroll
  for (int e = 0; e < E_NUM; ++e) {
#pragma unroll
    for (int rep = 0; rep < 4; ++rep) {
      const float4 rv =
          *(const float4*)(rw + (size_t)e * H_DIM + rep * 256 + lane * 4);
      acc[e] += xv[rep].x * rv.x + xv[rep].y * rv.y + xv[rep].z * rv.z +
                xv[rep].w * rv.w;
    }
  }

#pragma unroll
  for (int e = 0; e < E_NUM; ++e) {
    float v = acc[e];
#pragma unroll
    for (int off = 32; off > 0; off >>= 1) v += __shfl_xor(v, off);
    acc[e] = v;
  }

  if (lane < 2) {
    float s[E_NUM];
#pragma unroll
    for (int e = 0; e < E_NUM; ++e) s[e] = 1.f / (1.f + expf(-acc[e]));
    int i1 = 0;
    float v1 = s[0];
#pragma unroll
    for (int e = 1; e < E_NUM; ++e)
      if (s[e] > v1) { v1 = s[e]; i1 = e; }
    int i2 = -1;
    float v2 = -1.f;
#pragma unroll
    for (int e = 0; e < E_NUM; ++e)
      if (e != i1 && s[e] > v2) { v2 = s[e]; i2 = e; }
    const float inv = 1.f / (v1 + v2 + 1e-20f);
    const int pe = (lane == 0) ? i1 : i2;
    const float pw = ((lane == 0) ? v1 : v2) * inv;
    const int slot = atomicAdd(&counts[pe * CPAD], 1);
    tokens[pe * T_TOK + slot] = t;
    wts[pe * T_TOK + slot] = pw;
    rows[t * 2 + lane] = pe * 4096 + slot;
  }
}

// ---------------------------------------------------------------------------
// Kernel 2: exclusive prefix sum over the 16 (padded) expert counts.
// ---------------------------------------------------------------------------
__global__ void offsets_kernel(const int* __restrict__ counts,
                               int* __restrict__ offsets) {
  if (threadIdx.x == 0) {
    int a = 0;
    for (int e = 0; e < E_NUM; ++e) {
      offsets[e] = a;
      a += counts[e * CPAD];
    }
    offsets[E_NUM] = a;
  }
}

#define FENCE() __builtin_amdgcn_sched_barrier(0)

// ---------------------------------------------------------------------------
// REAL gemm1 (byte-identical to R7, passing): counted-vmcnt pipeline.
// ---------------------------------------------------------------------------
__global__ __launch_bounds__(256, 2) void gemm1_kernel(
    const uint16_t* __restrict__ xbf, const float* __restrict__ gate,
    const float* __restrict__ up, const int* __restrict__ counts,
    const int* __restrict__ offsets, const int* __restrict__ tokens,
    const float* __restrict__ wts, uint16_t* __restrict__ hbuf) {
  const int e = blockIdx.z;
  const int count = counts[e * CPAD];
  const int m0 = blockIdx.y * 128;
  if (m0 >= count) return;
  const int n0 = blockIdx.x * 64;

  __shared__ __align__(16) uint16_t As[2][128 * 64];  // 32 KB
  __shared__ __align__(16) uint16_t Bgs[2][64 * 64];  // 16 KB
  __shared__ __align__(16) uint16_t Bus[2][64 * 64];  // 16 KB
  __shared__ int tok_s[128];
  __shared__ float wt_s[128];

  const int tid = threadIdx.x;
  if (tid < 128) {
    const int slot = m0 + tid;
    int tk = 0;
    float w = 0.f;
    if (slot < count) {
      tk = tokens[e * T_TOK + slot];
      w = wts[e * T_TOK + slot];
    }
    tok_s[tid] = tk;
    wt_s[tid] = w;
  }
  __syncthreads();

  const uint16_t* a_g[4];
  int a_c[4];
#pragma unroll
  for (int j = 0; j < 4; ++j) {
    const int c = j * 256 + tid;
    const int m = c >> 3;
    const int kq = (c & 7) ^ (m & 7);
    a_g[j] = xbf + (size_t)tok_s[m] * H_DIM + kq * 8;
    a_c[j] = c * 8;
  }
  const int bm = tid >> 3;
  const int bkq = (tid & 7) ^ (bm & 7);
  const float* gp0 = gate + ((size_t)e * I_DIM + n0 + bm) * H_DIM + bkq * 8;
  const float* gp1 = gp0 + 32 * H_DIM;
  const float* uq0 = up + ((size_t)e * I_DIM + n0 + bm) * H_DIM + bkq * 8;
  const float* uq1 = uq0 + 32 * H_DIM;
  const int bc0 = tid * 8, bc1 = (tid + 256) * 8;

  const int wave = tid >> 6, lane = tid & 63;
  const int wm = wave * 32;
  const int lc = lane & 15, lq = lane >> 4;
  const int l7 = lc & 7;

  f32x4 accg[2][4], accu[2][4];
  const f32x4 zero4 = {0.f, 0.f, 0.f, 0.f};
#pragma unroll
  for (int i = 0; i < 2; ++i)
#pragma unroll
    for (int j = 0; j < 4; ++j) {
      accg[i][j] = zero4;
      accu[i][j] = zero4;
    }

  int am[2], bn[4];
#pragma unroll
  for (int i = 0; i < 2; ++i) am[i] = (wm + i * 16 + lc) * 64;
#pragma unroll
  for (int i = 0; i < 4; ++i) bn[i] = (i * 16 + lc) * 64;

  float4 bA[8];
  float4 bB[8];

#define G1_STAGE(BUF, KT)                                                 \
  {                                                                       \
    const int ko_ = (KT)*64;                                              \
    _Pragma("unroll") for (int j = 0; j < 4; ++j)                         \
        async_copy16(a_g[j] + ko_, &As[BUF][a_c[j]]);                     \
  }

#define G1_LOADB(KT, v)                                                   \
  v[0] = *(const float4*)(gp0 + (KT)*64);                                 \
  v[1] = *(const float4*)(gp0 + (KT)*64 + 4);                             \
  v[2] = *(const float4*)(gp1 + (KT)*64);                                 \
  v[3] = *(const float4*)(gp1 + (KT)*64 + 4);                             \
  v[4] = *(const float4*)(uq0 + (KT)*64);                                 \
  v[5] = *(const float4*)(uq0 + (KT)*64 + 4);                             \
  v[6] = *(const float4*)(uq1 + (KT)*64);                                 \
  v[7] = *(const float4*)(uq1 + (KT)*64 + 4);

#define G1_WRITEB(BUF, v)                                                 \
  {                                                                       \
    uint4 p;                                                              \
    p.x = pk2bf(v[0].x, v[0].y); p.y = pk2bf(v[0].z, v[0].w);             \
    p.z = pk2bf(v[1].x, v[1].y); p.w = pk2bf(v[1].z, v[1].w);             \
    *(uint4*)&Bgs[BUF][bc0] = p;                                          \
    p.x = pk2bf(v[2].x, v[2].y); p.y = pk2bf(v[2].z, v[2].w);             \
    p.z = pk2bf(v[3].x, v[3].y); p.w = pk2bf(v[3].z, v[3].w);             \
    *(uint4*)&Bgs[BUF][bc1] = p;                                          \
    p.x = pk2bf(v[4].x, v[4].y); p.y = pk2bf(v[4].z, v[4].w);             \
    p.z = pk2bf(v[5].x, v[5].y); p.w = pk2bf(v[5].z, v[5].w);             \
    *(uint4*)&Bus[BUF][bc0] = p;                                          \
    p.x = pk2bf(v[6].x, v[6].y); p.y = pk2bf(v[6].z, v[6].w);             \
    p.z = pk2bf(v[7].x, v[7].y); p.w = pk2bf(v[7].z, v[7].w);             \
    *(uint4*)&Bus[BUF][bc1] = p;                                          \
  }

#define G1_COMPUTE(CB)                                                    \
  _Pragma("unroll") for (int ks = 0; ks < 2; ++ks) {                      \
    const int kswz = ((ks * 4 + lq) ^ l7) * 8;                            \
    bf16x8 af[2], bg[4], bu[4];                                           \
    _Pragma("unroll") for (int i = 0; i < 2; ++i) af[i] =                 \
        *(const bf16x8*)&As[CB][am[i] + kswz];                            \
    _Pragma("unroll") for (int i = 0; i < 4; ++i) {                       \
      bg[i] = *(const bf16x8*)&Bgs[CB][bn[i] + kswz];                     \
      bu[i] = *(const bf16x8*)&Bus[CB][bn[i] + kswz];                     \
    }                                                                     \
    _Pragma("unroll") for (int im = 0; im < 2; ++im)                      \
        _Pragma("unroll") for (int in = 0; in < 4; ++in) {                \
      accg[im][in] = __builtin_amdgcn_mfma_f32_16x16x32_bf16(             \
          af[im], bg[in], accg[im][in], 0, 0, 0);                         \
      accu[im][in] = __builtin_amdgcn_mfma_f32_16x16x32_bf16(             \
          af[im], bu[in], accu[im][in], 0, 0, 0);                         \
    }                                                                     \
  }

  G1_STAGE(0, 0)
  G1_LOADB(0, bA)
  G1_LOADB(1, bB)
  asm volatile("s_waitcnt vmcnt(8)" ::: "memory");
  FENCE();
  G1_WRITEB(0, bA)
  asm volatile("s_waitcnt lgkmcnt(0)" ::: "memory");
  FENCE();
  __builtin_amdgcn_s_barrier();
  FENCE();

  int cur = 0;
#pragma unroll 1
  for (int t2 = 0; t2 < 7; ++t2) {
    const int t = t2 * 2;
    G1_STAGE(cur ^ 1, t + 1)
    G1_LOADB(t + 2, bA)
    G1_COMPUTE(cur)
    asm volatile("s_waitcnt vmcnt(12)" ::: "memory");
    FENCE();
    G1_WRITEB(cur ^ 1, bB)
    asm volatile("s_waitcnt vmcnt(8) lgkmcnt(0)" ::: "memory");
    FENCE();
    __builtin_amdgcn_s_barrier();
    FENCE();
    cur ^= 1;
    G1_STAGE(cur ^ 1, t + 2)
    G1_LOADB(t + 3, bB)
    G1_COMPUTE(cur)
    asm volatile("s_waitcnt vmcnt(12)" ::: "memory");
    FENCE();
    G1_WRITEB(cur ^ 1, bA)
    asm volatile("s_waitcnt vmcnt(8) lgkmcnt(0)" ::: "memory");
    FENCE();
    __builtin_amdgcn_s_barrier();
    FENCE();
    cur ^= 1;
  }
  G1_STAGE(cur ^ 1, 15)
  G1_COMPUTE(cur)
  asm volatile("s_waitcnt vmcnt(4)" ::: "memory");
  FENCE();
  G1_WRITEB(cur ^ 1, bB)
  asm volatile("s_waitcnt vmcnt(0) lgkmcnt(0)" ::: "memory");
  FENCE();
  __builtin_amdgcn_s_barrier();
  FENCE();
  cur ^= 1;
  G1_COMPUTE(cur)

  const int off_e = offsets[e];
#pragma unroll
  for (int im = 0; im < 2; ++im) {
#pragma unroll
    for (int r = 0; r < 4; ++r) {
      const int row = wm + im * 16 + lq * 4 + r;
      const int slot = m0 + row;
      if (slot < count) {
        const float w = wt_s[row];
        uint16_t* hrow = hbuf + (size_t)(off_e + slot) * I_DIM + n0;
#pragma unroll
        for (int in = 0; in < 4; ++in) {
          const float g = accg[im][in][r];
          const float u = accu[im][in][r];
          const float hv = g / (1.f + __expf(-g)) * u * w;
          hrow[in * 16 + lc] = (uint16_t)f2bf(hv);
        }
      }
    }
  }
}

// ---------------------------------------------------------------------------
// R10 ablation probes — standalone, non-template, minimal.
// ---------------------------------------------------------------------------

// probe_skel: barriers + MFMA only, same LDS residency (2 blocks/CU).
__global__ __launch_bounds__(256, 2) void probe_skel(
    const int* __restrict__ counts, uint16_t* __restrict__ sink) {
  const int e = blockIdx.z;
  const int count = counts[e * CPAD];
  const int m0 = blockIdx.y * 128;
  if (m0 >= count) return;

  __shared__ uint8_t padlds[65536];  // match gemm1's 64KB residency
  const int tid = threadIdx.x;
  padlds[tid] = (uint8_t)tid;

  const short s0 = (short)(tid * 3 + 1);
  bf16x8 af[2], bg[4], bu[4];
#pragma unroll
  for (int i = 0; i < 2; ++i)
    af[i] = (bf16x8){s0, s0, s0, s0, s0, s0, s0, s0};
#pragma unroll
  for (int i = 0; i < 4; ++i) {
    const short si = (short)(s0 + i);
    bg[i] = (bf16x8){si, si, si, si, si, si, si, si};
    bu[i] = (bf16x8){si, si, si, si, si, si, si, si};
  }
  f32x4 accg[2][4], accu[2][4];
  const f32x4 zero4 = {0.f, 0.f, 0.f, 0.f};
#pragma unroll
  for (int i = 0; i < 2; ++i)
#pragma unroll
    for (int j = 0; j < 4; ++j) {
      accg[i][j] = zero4;
      accu[i][j] = zero4;
    }

#pragma unroll 1
  for (int t = 0; t < 16; ++t) {
#pragma unroll
    for (int ks = 0; ks < 2; ++ks)
#pragma unroll
      for (int im = 0; im < 2; ++im)
#pragma unroll
        for (int in = 0; in < 4; ++in) {
          accg[im][in] = __builtin_amdgcn_mfma_f32_16x16x32_bf16(
              af[im], bg[in], accg[im][in], 0, 0, 0);
          accu[im][in] = __builtin_amdgcn_mfma_f32_16x16x32_bf16(
              af[im], bu[in], accu[im][in], 0, 0, 0);
        }
    FENCE();
    __builtin_amdgcn_s_barrier();
    FENCE();
  }

  float s = (float)padlds[(tid + 1) & 255];
#pragma unroll
  for (int i = 0; i < 2; ++i)
#pragma unroll
    for (int j = 0; j < 4; ++j)
      s += accg[i][j][0] + accu[i][j][3];
  sink[((blockIdx.z * 2 + blockIdx.y) * 16 + blockIdx.x) * 256 + tid] =
      (uint16_t)f2bf(s);
}

// probe_a: A token-gather global_load_lds path only, counted vmcnt(4).
__global__ __launch_bounds__(256, 2) void probe_a(
    const uint16_t* __restrict__ xbf, const int* __restrict__ counts,
    const int* __restrict__ tokens, uint32_t* __restrict__ sink) {
  const int e = blockIdx.z;
  const int count = counts[e * CPAD];
  const int m0 = blockIdx.y * 128;
  if (m0 >= count) return;

  __shared__ __align__(16) uint16_t As[2][128 * 64];
  __shared__ int tok_s[128];

  const int tid = threadIdx.x;
  if (tid < 128) {
    const int slot = m0 + tid;
    tok_s[tid] = (slot < count) ? tokens[e * T_TOK + slot] : 0;
  }
  __syncthreads();

  const uint16_t* a_g[4];
  int a_c[4];
#pragma unroll
  for (int j = 0; j < 4; ++j) {
    const int c = j * 256 + tid;
    const int m = c >> 3;
    const int kq = (c & 7) ^ (m & 7);
    a_g[j] = xbf + (size_t)tok_s[m] * H_DIM + kq * 8;
    a_c[j] = c * 8;
  }

  G1_STAGE(0, 0)
  int cur = 0;
#pragma unroll 1
  for (int t = 0; t < 15; ++t) {
    G1_STAGE(cur ^ 1, t + 1)
    asm volatile("s_waitcnt vmcnt(4)" ::: "memory");
    FENCE();
    __builtin_amdgcn_s_barrier();
    FENCE();
    cur ^= 1;
  }
  asm volatile("s_waitcnt vmcnt(0)" ::: "memory");
  FENCE();
  __builtin_amdgcn_s_barrier();
  FENCE();

  uint32_t ka = *(const uint32_t*)&As[0][a_c[0]] ^
                *(const uint32_t*)&As[1][a_c[1]];
  sink[((blockIdx.z * 2 + blockIdx.y) * 16 + blockIdx.x) * 256 + tid] = ka;
}

// probe_b: fp32 B stream -> regs -> bf16 convert -> LDS, counted vmcnt(8).
__global__ __launch_bounds__(256, 2) void probe_b(
    const float* __restrict__ gate, const float* __restrict__ up,
    const int* __restrict__ counts, uint32_t* __restrict__ sink) {
  const int e = blockIdx.z;
  const int count = counts[e * CPAD];
  const int m0 = blockIdx.y * 128;
  if (m0 >= count) return;
  const int n0 = blockIdx.x * 64;

  __shared__ __align__(16) uint16_t Bgs[2][64 * 64];
  __shared__ __align__(16) uint16_t Bus[2][64 * 64];

  const int tid = threadIdx.x;
  const int bm = tid >> 3;
  const int bkq = (tid & 7) ^ (bm & 7);
  const float* gp0 = gate + ((size_t)e * I_DIM + n0 + bm) * H_DIM + bkq * 8;
  const float* gp1 = gp0 + 32 * H_DIM;
  const float* uq0 = up + ((size_t)e * I_DIM + n0 + bm) * H_DIM + bkq * 8;
  const float* uq1 = uq0 + 32 * H_DIM;
  const int bc0 = tid * 8, bc1 = (tid + 256) * 8;

  float4 bA[8];
  float4 bB[8];

  G1_LOADB(0, bA)
  G1_LOADB(1, bB)
  asm volatile("s_waitcnt vmcnt(8)" ::: "memory");
  FENCE();
  G1_WRITEB(0, bA)
  asm volatile("s_waitcnt lgkmcnt(0)" ::: "memory");
  FENCE();
  __builtin_amdgcn_s_barrier();
  FENCE();

  int cur = 0;
#pragma unroll 1
  for (int t2 = 0; t2 < 7; ++t2) {
    const int t = t2 * 2;
    G1_LOADB(t + 2, bA)
    asm volatile("s_waitcnt vmcnt(8)" ::: "memory");
    FENCE();
    G1_WRITEB(cur ^ 1, bB)
    asm volatile("s_waitcnt lgkmcnt(0)" ::: "memory");
    FENCE();
    __builtin_amdgcn_s_barrier();
    FENCE();
    cur ^= 1;
    G1_LOADB(t + 3, bB)
    asm volatile("s_waitcnt vmcnt(8)" ::: "memory");
    FENCE();
    G1_WRITEB(cur ^ 1, bA)
    asm volatile("s_waitcnt lgkmcnt(0)" ::: "memory");
    FENCE();
    __builtin_amdgcn_s_barrier();
    FENCE();
    cur ^= 1;
  }
  asm volatile("s_waitcnt vmcnt(0)" ::: "memory");
  FENCE();
  G1_WRITEB(cur ^ 1, bB)
  asm volatile("s_waitcnt lgkmcnt(0)" ::: "memory");
  FENCE();
  __builtin_amdgcn_s_barrier();
  FENCE();

  uint32_t ka = *(const uint32_t*)&Bgs[0][bc0] ^
                *(const uint32_t*)&Bus[1][bc1];
  sink[((blockIdx.z * 2 + blockIdx.y) * 16 + blockIdx.x) * 256 + tid] = ka;
}

// ---------------------------------------------------------------------------
// Kernel 4: GEMM2  obuf[row] = h[row] @ down_wT  (plain stores; combine sums)
// ---------------------------------------------------------------------------
__global__ __launch_bounds__(256, 3) void gemm2_kernel(
    const uint16_t* __restrict__ hbuf, const float* __restrict__ down,
    const int* __restrict__ counts, const int* __restrict__ offsets,
    float* __restrict__ obuf) {
  const int e = blockIdx.z;
  const int count = counts[e * CPAD];
  const int m0 = blockIdx.y * 128;
  if (m0 >= count) return;
  const int n0 = blockIdx.x * 64;

  __shared__ __align__(16) uint16_t As[2][128 * 64];
  __shared__ __align__(16) uint16_t Bs[2][64 * 64];

  const int tid = threadIdx.x;
  const int off_e = offsets[e];

  const uint16_t* a_g[4];
  int a_c[4];
#pragma unroll
  for (int j = 0; j < 4; ++j) {
    const int c = j * 256 + tid;
    const int m = c >> 3;
    const int kq = (c & 7) ^ (m & 7);
    int r = off_e + m0 + m;
    if (r > TOTAL_ROWS - 1) r = TOTAL_ROWS - 1;
    a_g[j] = hbuf + (size_t)r * I_DIM + kq * 8;
    a_c[j] = c * 8;
  }
  const int bm = tid >> 3;
  const int bkq = (tid & 7) ^ (bm & 7);
  const float* dp0 = down + ((size_t)e * H_DIM + n0 + bm) * I_DIM + bkq * 8;
  const float* dp1 = dp0 + 32 * I_DIM;
  const int bc0 = tid * 8, bc1 = (tid + 256) * 8;

  const int wave = tid >> 6, lane = tid & 63;
  const int wm = wave * 32;
  const int lc = lane & 15, lq = lane >> 4;
  const int l7 = lc & 7;

  f32x4 acc[2][4];
  const f32x4 zero4 = {0.f, 0.f, 0.f, 0.f};
#pragma unroll
  for (int i = 0; i < 2; ++i)
#pragma unroll
    for (int j = 0; j < 4; ++j) acc[i][j] = zero4;

  int am[2], bn[4];
#pragma unroll
  for (int i = 0; i < 2; ++i) am[i] = (wm + i * 16 + lc) * 64;
#pragma unroll
  for (int i = 0; i < 4; ++i) bn[i] = (i * 16 + lc) * 64;

  float4 dA[4];
  float4 dB[4];

#define G2_STAGE(BUF, KT)                                                 \
  {                                                                       \
    const int ko_ = (KT)*64;                                              \
    _Pragma("unroll") for (int j = 0; j < 4; ++j)                         \
        async_copy16(a_g[j] + ko_, &As[BUF][a_c[j]]);                     \
  }

#define G2_LOADB(KT, v)                                                   \
  v[0] = *(const float4*)(dp0 + (KT)*64);                                 \
  v[1] = *(const float4*)(dp0 + (KT)*64 + 4);                             \
  v[2] = *(const float4*)(dp1 + (KT)*64);                                 \
  v[3] = *(const float4*)(dp1 + (KT)*64 + 4);

#define G2_WRITEB(BUF, v)                                                 \
  {                                                                       \
    uint4 p;                                                              \
    p.x = pk2bf(v[0].x, v[0].y); p.y = pk2bf(v[0].z, v[0].w);             \
    p.z = pk2bf(v[1].x, v[1].y); p.w = pk2bf(v[1].z, v[1].w);             \
    *(uint4*)&Bs[BUF][bc0] = p;                                           \
    p.x = pk2bf(v[2].x, v[2].y); p.y = pk2bf(v[2].z, v[2].w);             \
    p.z = pk2bf(v[3].x, v[3].y); p.w = pk2bf(v[3].z, v[3].w);             \
    *(uint4*)&Bs[BUF][bc1] = p;                                           \
  }

#define G2_COMPUTE(CB)                                                    \
  _Pragma("unroll") for (int ks = 0; ks < 2; ++ks) {                      \
    const int kswz = ((ks * 4 + lq) ^ l7) * 8;                            \
    bf16x8 af[2], bf[4];                                                  \
    _Pragma("unroll") for (int i = 0; i < 2; ++i) af[i] =                 \
        *(const bf16x8*)&As[CB][am[i] + kswz];                            \
    _Pragma("unroll") for (int i = 0; i < 4; ++i) bf[i] =                 \
        *(const bf16x8*)&Bs[CB][bn[i] + kswz];                            \
    _Pragma("unroll") for (int im = 0; im < 2; ++im)                      \
        _Pragma("unroll") for (int in = 0; in < 4; ++in) acc[im][in] =    \
            __builtin_amdgcn_mfma_f32_16x16x32_bf16(af[im], bf[in],       \
                                                    acc[im][in], 0, 0, 0);\
  }

  G2_STAGE(0, 0)
  G2_LOADB(0, dA)
  G2_LOADB(1, dB)
  asm volatile("s_waitcnt vmcnt(4)" ::: "memory");
  FENCE();
  G2_WRITEB(0, dA)
  asm volatile("s_waitcnt lgkmcnt(0)" ::: "memory");
  FENCE();
  __builtin_amdgcn_s_barrier();
  FENCE();

  int cur = 0;
#pragma unroll 1
  for (int t2 = 0; t2 < 7; ++t2) {
    const int t = t2 * 2;
    G2_STAGE(cur ^ 1, t + 1)
    G2_LOADB(t + 2, dA)
    G2_COMPUTE(cur)
    asm volatile("s_waitcnt vmcnt(8)" ::: "memory");
    FENCE();
    G2_WRITEB(cur ^ 1, dB)
    asm volatile("s_waitcnt vmcnt(4) lgkmcnt(0)" ::: "memory");
    FENCE();
    __builtin_amdgcn_s_barrier();
    FENCE();
    cur ^= 1;
    G2_STAGE(cur ^ 1, t + 2)
    G2_LOADB(t + 3, dB)
    G2_COMPUTE(cur)
    asm volatile("s_waitcnt vmcnt(8)" ::: "memory");
    FENCE();
    G2_WRITEB(cur ^ 1, dA)
    asm volatile("s_waitcnt vmcnt(4) lgkmcnt(0)" ::: "memory");
    FENCE();
    __builtin_amdgcn_s_barrier();
    FENCE();
    cur ^= 1;
  }
  G2_STAGE(cur ^ 1, 15)
  G2_COMPUTE(cur)
  asm volatile("s_waitcnt vmcnt(4)" ::: "memory");
  FENCE();
  G2_WRITEB(cur ^ 1, dB)
  asm volatile("s_waitcnt vmcnt(0) lgkmcnt(0)" ::: "memory");
  FENCE();
  __builtin_amdgcn_s_barrier();
  FENCE();
  cur ^= 1;
  G2_COMPUTE(cur)

#pragma unroll
  for (int im = 0; im < 2; ++im) {
#pragma unroll
    for (int r = 0; r < 4; ++r) {
      const int row = wm + im * 16 + lq * 4 + r;
      const int slot = m0 + row;
      if (slot < count) {
        float* orow = obuf + (size_t)(off_e + slot) * H_DIM + n0;
#pragma unroll
        for (int in = 0; in < 4; ++in)
          orow[in * 16 + lc] = acc[im][in][r];
      }
    }
  }
}

// ---------------------------------------------------------------------------
// Kernel 5: combine — out[t] = obuf[row(t,0)] + obuf[row(t,1)].
// ---------------------------------------------------------------------------
__global__ __launch_bounds__(256) void combine_kernel(
    const float* __restrict__ obuf, const int* __restrict__ rows,
    const int* __restrict__ offsets, float* __restrict__ out) {
  const int t = blockIdx.x;
  const int c = threadIdx.x * 4;
  const int e0 = rows[t * 2 + 0];
  const int e1 = rows[t * 2 + 1];
  const size_t r0 = offsets[e0 >> 12] + (e0 & 4095);
  const size_t r1 = offsets[e1 >> 12] + (e1 & 4095);
  const float4 a = *(const float4*)(obuf + r0 * H_DIM + c);
  const float4 b = *(const float4*)(obuf + r1 * H_DIM + c);
  float4 o;
  o.x = a.x + b.x;
  o.y = a.y + b.y;
  o.z = a.z + b.z;
  o.w = a.w + b.w;
  *(float4*)(out + (size_t)t * H_DIM + c) = o;
}

// ---------------------------------------------------------------------------
extern "C" void kernel_launch(void* const* d_in, const int* in_sizes, int n_in,
                              void* d_out, int out_size, void* d_ws,
                              size_t ws_size, hipStream_t stream) {
  const float* x = (const float*)d_in[0];
  const float* rw = (const float*)d_in[1];
  const float* gate = (const float*)d_in[2];
  const float* up = (const float*)d_in[3];
  const float* down = (const float*)d_in[4];
  float* out = (float*)d_out;

  uint8_t* ws = (uint8_t*)d_ws;
  int* counts = (int*)(ws + WS_COUNTS);
  int* offsets = (int*)(ws + WS_OFFSETS);
  int* rows = (int*)(ws + WS_ROWS);
  int* tokens = (int*)(ws + WS_TOKENS);
  float* wts = (float*)(ws + WS_WTS);
  uint16_t* xbf = (uint16_t*)(ws + WS_XBF);
  uint16_t* hbuf = (uint16_t*)(ws + WS_HBUF);
  float* obuf = (float*)(ws + WS_OBUF);
  // probe sinks live in obuf scratch (gemm2 fully overwrites afterwards)
  uint16_t* sink_skel = (uint16_t*)(ws + WS_OBUF);
  uint32_t* sink_a = (uint32_t*)(ws + WS_OBUF + 2097152);
  uint32_t* sink_b = (uint32_t*)(ws + WS_OBUF + 4194304);

  hipMemsetAsync(counts, 0, 2048, stream);

  router_kernel<<<512, 256, 0, stream>>>(x, rw, xbf, counts, tokens, wts,
                                         rows);
  offsets_kernel<<<1, 64, 0, stream>>>(counts, offsets);

  // --- ablation probes (diagnostic; outputs discarded) ---
  probe_skel<<<dim3(16, 16, 16), 256, 0, stream>>>(counts, sink_skel);
  probe_a<<<dim3(16, 16, 16), 256, 0, stream>>>(xbf, counts, tokens, sink_a);
  probe_b<<<dim3(16, 16, 16), 256, 0, stream>>>(gate, up, counts, sink_b);

  gemm1_kernel<<<dim3(16, 16, 16), 256, 0, stream>>>(
      xbf, gate, up, counts, offsets, tokens, wts, hbuf);
  gemm2_kernel<<<dim3(16, 16, 16), 256, 0, stream>>>(hbuf, down, counts,
                                                     offsets, obuf);
  combine_kernel<<<T_TOK, 256, 0, stream>>>(obuf, rows, offsets, out);
}